// Round 2
// baseline (13465.222 us; speedup 1.0000x reference)
//
#include <hip/hip_runtime.h>
#include <hip/hip_bf16.h>
#include <math.h>

typedef __attribute__((ext_vector_type(4))) float f32x4;
typedef __attribute__((ext_vector_type(8))) short bf16x8;

#define NB1 24   // blocks in GRU1 scan: 24 x 16 h-indices = 384

__device__ __forceinline__ unsigned short f2bf(float f){
  union { float f; unsigned int i; } c; c.f = f;
  return (unsigned short)((c.i + 0x7fffu + ((c.i >> 16) & 1u)) >> 16);
}
__device__ __forceinline__ float sigm(float x){
  return 1.0f / (1.0f + exp2f(-1.4426950408889634f * x));
}
__device__ __forceinline__ float tanh_(float x){
  float e = exp2f(2.8853900817779268f * x);
  return 1.0f - 2.0f / (e + 1.0f);
}

// ---------------- encoder: pitch-emb concat -> conv1 -> conv2 -> d1 -> d2 ----
__global__ void __launch_bounds__(128) encoder_kernel(
    const float* __restrict__ feat, const int* __restrict__ pitch,
    const float* __restrict__ emb_pitch,
    const float* __restrict__ w1, const float* __restrict__ b1,
    const float* __restrict__ w2, const float* __restrict__ b2,
    const float* __restrict__ d1w, const float* __restrict__ d1b,
    const float* __restrict__ d2w, const float* __restrict__ d2b,
    float* __restrict__ fout)
{
  int b = blockIdx.x, tid = threadIdx.x;
  __shared__ float xin[19][104];
  __shared__ float t1[17][128];
  __shared__ float t2[15][128];
  __shared__ float t3[15][128];
  for (int idx = tid; idx < 19*38; idx += 128){ int l = idx/38, c = idx-l*38; xin[l][c] = feat[(b*19+l)*38+c]; }
  for (int idx = tid; idx < 19*64; idx += 128){ int l = idx/64, c = idx-l*64; xin[l][38+c] = emb_pitch[pitch[b*19+l]*64+c]; }
  __syncthreads();
  { // conv1: 102ch, k=3, VALID -> 17 x 128
    int c = tid;
    float acc[17];
    float bias = b1[c];
#pragma unroll
    for (int l=0;l<17;++l) acc[l]=bias;
    for (int i=0;i<102;++i){
      const float* wp = w1 + (c*102+i)*3;
      float w0 = wp[0], wk1 = wp[1], wk2 = wp[2];
      float x[19];
#pragma unroll
      for (int l=0;l<19;++l) x[l]=xin[l][i];
#pragma unroll
      for (int l=0;l<17;++l) acc[l] += w0*x[l] + wk1*x[l+1] + wk2*x[l+2];
    }
#pragma unroll
    for (int l=0;l<17;++l) t1[l][c] = tanh_(acc[l]);
  }
  __syncthreads();
  { // conv2: 128ch, k=3 -> 15 x 128
    int c = tid;
    float acc[15];
    float bias = b2[c];
#pragma unroll
    for (int l=0;l<15;++l) acc[l]=bias;
    for (int i=0;i<128;++i){
      const float* wp = w2 + (c*128+i)*3;
      float w0 = wp[0], wk1 = wp[1], wk2 = wp[2];
      float x[17];
#pragma unroll
      for (int l=0;l<17;++l) x[l]=t1[l][i];
#pragma unroll
      for (int l=0;l<15;++l) acc[l] += w0*x[l] + wk1*x[l+1] + wk2*x[l+2];
    }
#pragma unroll
    for (int l=0;l<15;++l) t2[l][c] = tanh_(acc[l]);
  }
  __syncthreads();
  { // dense1
    int c = tid;
    float acc[15];
    float bias = d1b[c];
#pragma unroll
    for (int l=0;l<15;++l) acc[l]=bias;
    for (int i=0;i<128;++i){
      float w = d1w[c*128+i];
#pragma unroll
      for (int l=0;l<15;++l) acc[l] += w*t2[l][i];
    }
#pragma unroll
    for (int l=0;l<15;++l) t3[l][c] = tanh_(acc[l]);
  }
  __syncthreads();
  { // dense2 -> fout [b][15][128] fp32
    int c = tid;
    float acc[15];
    float bias = d2b[c];
#pragma unroll
    for (int l=0;l<15;++l) acc[l]=bias;
    for (int i=0;i<128;++i){
      float w = d2w[c*128+i];
#pragma unroll
      for (int l=0;l<15;++l) acc[l] += w*t3[l][i];
    }
#pragma unroll
    for (int l=0;l<15;++l) fout[(b*15+l)*128+c] = tanh_(acc[l]);
  }
}

// ------- tables: Tp[j][v][jg][gate] = sum_i emb_pcm[v][i]*g1_wih[gate*384+jg][128j+i]
__global__ void __launch_bounds__(256) tables_kernel(
    const float* __restrict__ emb_pcm, const float* __restrict__ wih1,
    float* __restrict__ Tp)
{
  int v = blockIdx.x & 255, j = blockIdx.x >> 8;
  int tid = threadIdx.x;
  __shared__ float e[128];
  if (tid < 128) e[tid] = emb_pcm[v*128+tid];
  __syncthreads();
  for (int g = tid; g < 1152; g += 256){
    const float* wrow = wih1 + g*512 + j*128;
    float acc = 0.f;
    for (int i=0;i<128;i+=4){
      float4 u = *(const float4*)(wrow + i);
      acc += u.x*e[i+0]+u.y*e[i+1]+u.z*e[i+2]+u.w*e[i+3];
    }
    int gate = g/384, jg = g - gate*384;
    Tp[(j*256+v)*1536 + jg*4 + gate] = acc;
  }
}

// ------- per-frame feature gate terms (incl. input bias) for GRU1 (packed) and GRU2
__global__ void __launch_bounds__(256) fg_kernel(
    const float* __restrict__ f,
    const float* __restrict__ wih1, const float* __restrict__ bih1,
    const float* __restrict__ wih2, const float* __restrict__ bih2,
    float* __restrict__ Fg1p, float* __restrict__ Fg2)
{
  int bf_ = blockIdx.x; // b*15 + frame
  int tid = threadIdx.x;
  __shared__ float fr[128];
  if (tid < 128) fr[tid] = f[bf_*128+tid];
  __syncthreads();
  for (int g = tid; g < 1152; g += 256){
    const float* wrow = wih1 + g*512 + 384;
    float acc = bih1[g];
    for (int i=0;i<128;i+=4){
      float4 u = *(const float4*)(wrow + i);
      acc += u.x*fr[i+0]+u.y*fr[i+1]+u.z*fr[i+2]+u.w*fr[i+3];
    }
    int gate = g/384, jg = g - gate*384;
    Fg1p[bf_*1536 + jg*4 + gate] = acc;
  }
  if (tid < 48){
    const float* wrow = wih2 + tid*512 + 384;
    float acc = bih2[tid];
    for (int i=0;i<128;i+=4){
      float4 u = *(const float4*)(wrow + i);
      acc += u.x*fr[i+0]+u.y*fr[i+1]+u.z*fr[i+2]+u.w*fr[i+3];
    }
    Fg2[bf_*48+tid] = acc;
  }
}

// ------- GRU1 scan: 24 persistent 1-wave blocks, whh b-frags in VGPRs, MFMA M=16=batch
__global__ void __launch_bounds__(64) gru1_scan(
    const int* __restrict__ pcm, const float* __restrict__ whh,
    const float* __restrict__ bhh,
    const float* __restrict__ Tp, const float* __restrict__ Fg1p,
    unsigned short* __restrict__ hbuf, int* __restrict__ flags,
    unsigned short* __restrict__ out1)
{
  int blk = blockIdx.x;
  int l = threadIdx.x;
  int q = l >> 4, n = l & 15;
  int jg = blk*16 + n;
  int jg4 = jg*4;

  // b-fragments: W[gate][kk] : B[k][n'] = whh[gate*384 + jg][kk*32 + q*8 + i]  (fp32 -> bf16)
  bf16x8 W[3][12];
#pragma unroll
  for (int gate=0; gate<3; ++gate){
    const float* wr = whh + (gate*384 + jg)*384;
#pragma unroll
    for (int kk=0; kk<12; ++kk){
#pragma unroll
      for (int jj=0; jj<8; ++jj) W[gate][kk][jj] = (short)f2bf(wr[kk*32 + q*8 + jj]);
    }
  }
  float bhr = bhh[jg], bhz = bhh[384+jg], bhn = bhh[768+jg];
  float hown[4] = {0.f,0.f,0.f,0.f};
  const float* T1p = Tp + 256*1536;
  const float* T2p = Tp + 2*256*1536;
  int frame = 0, cnt = 0;

  for (int t = 1; t <= 2400; ++t){
    int tt = t-1;
    // ---- gather gx (independent of h; in flight during the flag poll) ----
    float xr[4], xz[4], xn[4];
#pragma unroll
    for (int r=0;r<4;++r){
      int b = (q<<2) + r;
      const int* pp = pcm + (b*2400 + tt)*3;
      int i0 = pp[0], i1 = pp[1], i2 = pp[2];
      float4 a0 = *(const float4*)(Tp  + i0*1536 + jg4);
      float4 a1 = *(const float4*)(T1p + i1*1536 + jg4);
      float4 a2 = *(const float4*)(T2p + i2*1536 + jg4);
      float4 af = *(const float4*)(Fg1p + (b*15+frame)*1536 + jg4);
      xr[r] = a0.x+a1.x+a2.x+af.x;
      xz[r] = a0.y+a1.y+a2.y+af.y;
      xn[r] = a0.z+a1.z+a2.z+af.z;
    }
    f32x4 accr = {0.f,0.f,0.f,0.f}, accz = {0.f,0.f,0.f,0.f}, accn = {0.f,0.f,0.f,0.f};
    if (t > 1){
      int need = t-1;
      for (;;){
        int v = need;
        if (l < NB1) v = __hip_atomic_load(flags + l*16, __ATOMIC_RELAXED, __HIP_MEMORY_SCOPE_AGENT);
        if (__all(v >= need)) break;
      }
      __threadfence();  // acquire: order/invalidate before reading h
      const unsigned short* hrow = hbuf + (tt&1)*6144 + n*384 + q*8;
      bf16x8 A[12];
#pragma unroll
      for (int kk=0;kk<12;++kk) A[kk] = *(const bf16x8*)(hrow + kk*32);
#pragma unroll
      for (int kk=0;kk<12;++kk){
        accr = __builtin_amdgcn_mfma_f32_16x16x32_bf16(A[kk], W[0][kk], accr, 0,0,0);
        accz = __builtin_amdgcn_mfma_f32_16x16x32_bf16(A[kk], W[1][kk], accz, 0,0,0);
        accn = __builtin_amdgcn_mfma_f32_16x16x32_bf16(A[kk], W[2][kk], accn, 0,0,0);
      }
    }
    unsigned short hb[4];
#pragma unroll
    for (int r=0;r<4;++r){
      float hr = accr[r]+bhr, hz = accz[r]+bhz, hn_ = accn[r]+bhn;
      float rg = sigm(xr[r]+hr);
      float zg = sigm(xz[r]+hz);
      float ng = tanh_(xn[r]+rg*hn_);
      float h = (1.f-zg)*ng + zg*hown[r];
      hown[r] = h;
      hb[r] = f2bf(h);
      hbuf[(t&1)*6144 + ((q<<2)+r)*384 + jg] = hb[r];
    }
    __threadfence();  // release h stores
    if (l == 0) __hip_atomic_store(flags + blk*16, t, __ATOMIC_RELEASE, __HIP_MEMORY_SCOPE_AGENT);
#pragma unroll
    for (int r=0;r<4;++r) out1[(((q<<2)+r)*2400 + tt)*384 + jg] = hb[r];
    if (++cnt == 160){ cnt = 0; ++frame; }
  }
}

// ------- gx2 = out1 @ g2_wih[:, :384].T + Fg2 (bias folded in Fg2)
__global__ void __launch_bounds__(256) gx2_kernel(
    const unsigned short* __restrict__ out1, const float* __restrict__ wih2,
    const float* __restrict__ Fg2, float* __restrict__ gx2)
{
  int tile = blockIdx.x, b = blockIdx.y;
  int tid = threadIdx.x;
  __shared__ float wl[48*388];
  __shared__ unsigned short xl[16*392];
  for (int v = tid; v < 48*96; v += 256){
    int row = v/96, c4 = (v - row*96)*4;
    *(float4*)(wl + row*388 + c4) = *(const float4*)(wih2 + row*512 + c4);
  }
  for (int v = tid; v < 16*48; v += 256){
    int row = v/48, c8 = (v - row*48)*8;
    *(uint4*)(xl + row*392 + c8) = *(const uint4*)(out1 + (b*2400 + tile*16 + row)*384 + c8);
  }
  __syncthreads();
  for (int o = tid; o < 768; o += 256){
    int g = o >> 4, tl = o & 15;            // consecutive threads share g -> broadcast reads
    int tg = tile*16 + tl, fr = tg/160;
    float acc = Fg2[(b*15+fr)*48 + g];
    const unsigned short* xp = xl + tl*392;
    const float* wp = wl + g*388;
    for (int i=0;i<384;++i){
      union { unsigned int u; float f; } cv; cv.u = ((unsigned int)xp[i]) << 16;
      acc += cv.f * wp[i];
    }
    gx2[(b*2400+tg)*48 + g] = acc;
  }
}

// ------- GRU2 scan: 16 blocks (1 batch each), zero-padded 16x16x32 MFMA
__global__ void __launch_bounds__(64) gru2_scan(
    const float* __restrict__ gx2, const float* __restrict__ whh2,
    const float* __restrict__ bhh2, float* __restrict__ out2)
{
  int b = blockIdx.x, l = threadIdx.x;
  int q = l >> 4, n = l & 15;
  __shared__ unsigned short hs[32];
  __shared__ float gxs[16*48];
  if (l < 32) hs[l] = 0;
  bf16x8 Wr = {0,0,0,0,0,0,0,0}, Wz = {0,0,0,0,0,0,0,0}, Wn = {0,0,0,0,0,0,0,0};
  if (q < 2){
#pragma unroll
    for (int jj=0; jj<8; ++jj){
      Wr[jj] = (short)f2bf(whh2[(n)*16 + q*8 + jj]);
      Wz[jj] = (short)f2bf(whh2[(16+n)*16 + q*8 + jj]);
      Wn[jj] = (short)f2bf(whh2[(32+n)*16 + q*8 + jj]);
    }
  }
  float bh_r=0.f, bh_z=0.f, bh_n=0.f, h=0.f;
  if (l < 16){ bh_r = bhh2[l]; bh_z = bhh2[16+l]; bh_n = bhh2[32+l]; }
  const float* src = gx2 + b*2400*48;
  float4 p0 = ((const float4*)src)[l];
  float4 p1 = ((const float4*)src)[l+64];
  float4 p2 = ((const float4*)src)[l+128];
  __syncthreads();
  for (int t=0; t<2400; ++t){
    int ph = t & 15;
    if (ph == 0){
      __syncthreads();
      ((float4*)gxs)[l] = p0; ((float4*)gxs)[l+64] = p1; ((float4*)gxs)[l+128] = p2;
      if (t+16 < 2400){
        const float4* s2 = (const float4*)(src + (t+16)*48);
        p0 = s2[l]; p1 = s2[l+64]; p2 = s2[l+128];
      }
      __syncthreads();
    }
    bf16x8 a = {0,0,0,0,0,0,0,0};
    if (n == 0) a = *(const bf16x8*)(hs + q*8);
    f32x4 z4 = {0.f,0.f,0.f,0.f};
    f32x4 dr = __builtin_amdgcn_mfma_f32_16x16x32_bf16(a, Wr, z4, 0,0,0);
    f32x4 dz = __builtin_amdgcn_mfma_f32_16x16x32_bf16(a, Wz, z4, 0,0,0);
    f32x4 dn = __builtin_amdgcn_mfma_f32_16x16x32_bf16(a, Wn, z4, 0,0,0);
    if (l < 16){
      const float* g = gxs + ph*48;
      float rg = sigm(g[l] + dr[0] + bh_r);
      float zg = sigm(g[16+l] + dz[0] + bh_z);
      float ng = tanh_(g[32+l] + rg*(dn[0] + bh_n));
      h = (1.f - zg)*ng + zg*h;
      hs[l] = f2bf(h);
      out2[(b*2400+t)*16 + l] = h;
    }
    __syncthreads();
  }
}

// ------- MDense head
__global__ void __launch_bounds__(256) head_kernel(
    const float* __restrict__ out2,
    const float* __restrict__ fc1w, const float* __restrict__ fc1b,
    const float* __restrict__ fc2w, const float* __restrict__ fc2b,
    const float* __restrict__ g1, const float* __restrict__ g2,
    float* __restrict__ out)
{
  int blk = blockIdx.x;
  int b = blk/150, tile = blk - b*150;
  int c = threadIdx.x;
  __shared__ float s[256];
  float w1[16], w2[16];
#pragma unroll
  for (int k=0;k<16;k+=4){
    float4 u = *(const float4*)(fc1w + c*16 + k);
    w1[k]=u.x; w1[k+1]=u.y; w1[k+2]=u.z; w1[k+3]=u.w;
    float4 v = *(const float4*)(fc2w + c*16 + k);
    w2[k]=v.x; w2[k+1]=v.y; w2[k+2]=v.z; w2[k+3]=v.w;
  }
  float b1 = fc1b[c], b2 = fc2b[c];
  float ga = g1[c], gb = g2[c];
  int base = b*2400 + tile*16;
  s[c] = out2[base*16 + c];
  __syncthreads();
  for (int tl=0; tl<16; ++tl){
    float a1=b1, a2=b2;
#pragma unroll
    for (int k=0;k<16;++k){ float x = s[tl*16+k]; a1 += x*w1[k]; a2 += x*w2[k]; }
    float y = ga*tanh_(a1) + gb*tanh_(a2);
    out[(base+tl)*256 + c] = y;
  }
}

extern "C" void kernel_launch(void* const* d_in, const int* in_sizes, int n_in,
                              void* d_out, int out_size, void* d_ws, size_t ws_size,
                              hipStream_t stream)
{
  const int*   pcm      = (const int*)d_in[0];
  const float* feat     = (const float*)d_in[1];
  const int*   pitch    = (const int*)d_in[2];
  const float* emb_pcm  = (const float*)d_in[3];
  const float* emb_pit  = (const float*)d_in[4];
  const float* conv1_w  = (const float*)d_in[5];
  const float* conv1_b  = (const float*)d_in[6];
  const float* conv2_w  = (const float*)d_in[7];
  const float* conv2_b  = (const float*)d_in[8];
  const float* d1_w     = (const float*)d_in[9];
  const float* d1_b     = (const float*)d_in[10];
  const float* d2_w     = (const float*)d_in[11];
  const float* d2_b     = (const float*)d_in[12];
  const float* g1_wih   = (const float*)d_in[13];
  const float* g1_whh   = (const float*)d_in[14];
  const float* g1_bih   = (const float*)d_in[15];
  const float* g1_bhh   = (const float*)d_in[16];
  const float* g2_wih   = (const float*)d_in[17];
  const float* g2_whh   = (const float*)d_in[18];
  const float* g2_bih   = (const float*)d_in[19];
  const float* g2_bhh   = (const float*)d_in[20];
  const float* fc1_w    = (const float*)d_in[21];
  const float* fc1_b    = (const float*)d_in[22];
  const float* fc2_w    = (const float*)d_in[23];
  const float* fc2_b    = (const float*)d_in[24];
  const float* gamma1   = (const float*)d_in[25];
  const float* gamma2   = (const float*)d_in[26];

  char* ws = (char*)d_ws;
  int*            flags = (int*)(ws + 0);                       //  2048 B
  float*          f_ws  = (float*)(ws + 2048);                  //  122880 B
  float*          Tp    = (float*)(ws + 131072);                //  4718592 B
  float*          Fg1p  = (float*)(ws + 4849664);               //  1474560 B
  float*          Fg2   = (float*)(ws + 6324224);               //  46080 B
  unsigned short* hbuf  = (unsigned short*)(ws + 6370304);      //  24576 B
  unsigned short* out1  = (unsigned short*)(ws + 6394880);      //  29491200 B
  float*          gx2   = (float*)(ws + 35886080);              //  7372800 B
  float*          out2  = (float*)(ws + 43258880);              //  2457600 B  (end ~45.7 MB)

  hipMemsetAsync(flags, 0, 2048, stream);
  encoder_kernel<<<16, 128, 0, stream>>>(feat, pitch, emb_pit, conv1_w, conv1_b,
                                         conv2_w, conv2_b, d1_w, d1_b, d2_w, d2_b, f_ws);
  tables_kernel<<<768, 256, 0, stream>>>(emb_pcm, g1_wih, Tp);
  fg_kernel<<<240, 256, 0, stream>>>(f_ws, g1_wih, g1_bih, g2_wih, g2_bih, Fg1p, Fg2);
  gru1_scan<<<NB1, 64, 0, stream>>>(pcm, g1_whh, g1_bhh, Tp, Fg1p, hbuf, flags, out1);
  gx2_kernel<<<dim3(150,16), 256, 0, stream>>>(out1, g2_wih, Fg2, gx2);
  gru2_scan<<<16, 64, 0, stream>>>(gx2, g2_whh, g2_bhh, out2);
  head_kernel<<<2400, 256, 0, stream>>>(out2, fc1_w, fc1_b, fc2_w, fc2_b, gamma1, gamma2,
                                        (float*)d_out);
}

// Round 3
// 12828.065 us; speedup vs baseline: 1.0497x; 1.0497x over previous
//
#include <hip/hip_runtime.h>
#include <hip/hip_bf16.h>
#include <math.h>

typedef __attribute__((ext_vector_type(4))) float f32x4;
typedef __attribute__((ext_vector_type(8))) short bf16x8;

#define NB1 24   // blocks in GRU1 scan: 24 x 16 h-indices = 384

__device__ __forceinline__ unsigned short f2bf(float f){
  union { float f; unsigned int i; } c; c.f = f;
  return (unsigned short)((c.i + 0x7fffu + ((c.i >> 16) & 1u)) >> 16);
}
__device__ __forceinline__ float sigm(float x){
  return 1.0f / (1.0f + exp2f(-1.4426950408889634f * x));
}
__device__ __forceinline__ float tanh_(float x){
  float e = exp2f(2.8853900817779268f * x);
  return 1.0f - 2.0f / (e + 1.0f);
}

// ---------------- encoder: pitch-emb concat -> conv1 -> conv2 -> d1 -> d2 ----
__global__ void __launch_bounds__(128) encoder_kernel(
    const float* __restrict__ feat, const int* __restrict__ pitch,
    const float* __restrict__ emb_pitch,
    const float* __restrict__ w1, const float* __restrict__ b1,
    const float* __restrict__ w2, const float* __restrict__ b2,
    const float* __restrict__ d1w, const float* __restrict__ d1b,
    const float* __restrict__ d2w, const float* __restrict__ d2b,
    float* __restrict__ fout)
{
  int b = blockIdx.x, tid = threadIdx.x;
  __shared__ float xin[19][104];
  __shared__ float t1[17][128];
  __shared__ float t2[15][128];
  __shared__ float t3[15][128];
  for (int idx = tid; idx < 19*38; idx += 128){ int l = idx/38, c = idx-l*38; xin[l][c] = feat[(b*19+l)*38+c]; }
  for (int idx = tid; idx < 19*64; idx += 128){ int l = idx/64, c = idx-l*64; xin[l][38+c] = emb_pitch[pitch[b*19+l]*64+c]; }
  __syncthreads();
  { // conv1: 102ch, k=3, VALID -> 17 x 128
    int c = tid;
    float acc[17];
    float bias = b1[c];
#pragma unroll
    for (int l=0;l<17;++l) acc[l]=bias;
    for (int i=0;i<102;++i){
      const float* wp = w1 + (c*102+i)*3;
      float w0 = wp[0], wk1 = wp[1], wk2 = wp[2];
      float x[19];
#pragma unroll
      for (int l=0;l<19;++l) x[l]=xin[l][i];
#pragma unroll
      for (int l=0;l<17;++l) acc[l] += w0*x[l] + wk1*x[l+1] + wk2*x[l+2];
    }
#pragma unroll
    for (int l=0;l<17;++l) t1[l][c] = tanh_(acc[l]);
  }
  __syncthreads();
  { // conv2: 128ch, k=3 -> 15 x 128
    int c = tid;
    float acc[15];
    float bias = b2[c];
#pragma unroll
    for (int l=0;l<15;++l) acc[l]=bias;
    for (int i=0;i<128;++i){
      const float* wp = w2 + (c*128+i)*3;
      float w0 = wp[0], wk1 = wp[1], wk2 = wp[2];
      float x[17];
#pragma unroll
      for (int l=0;l<17;++l) x[l]=t1[l][i];
#pragma unroll
      for (int l=0;l<15;++l) acc[l] += w0*x[l] + wk1*x[l+1] + wk2*x[l+2];
    }
#pragma unroll
    for (int l=0;l<15;++l) t2[l][c] = tanh_(acc[l]);
  }
  __syncthreads();
  { // dense1
    int c = tid;
    float acc[15];
    float bias = d1b[c];
#pragma unroll
    for (int l=0;l<15;++l) acc[l]=bias;
    for (int i=0;i<128;++i){
      float w = d1w[c*128+i];
#pragma unroll
      for (int l=0;l<15;++l) acc[l] += w*t2[l][i];
    }
#pragma unroll
    for (int l=0;l<15;++l) t3[l][c] = tanh_(acc[l]);
  }
  __syncthreads();
  { // dense2 -> fout [b][15][128] fp32
    int c = tid;
    float acc[15];
    float bias = d2b[c];
#pragma unroll
    for (int l=0;l<15;++l) acc[l]=bias;
    for (int i=0;i<128;++i){
      float w = d2w[c*128+i];
#pragma unroll
      for (int l=0;l<15;++l) acc[l] += w*t3[l][i];
    }
#pragma unroll
    for (int l=0;l<15;++l) fout[(b*15+l)*128+c] = tanh_(acc[l]);
  }
}

// ------- tables: Tp[j][v][jg][gate] = sum_i emb_pcm[v][i]*g1_wih[gate*384+jg][128j+i]
__global__ void __launch_bounds__(256) tables_kernel(
    const float* __restrict__ emb_pcm, const float* __restrict__ wih1,
    float* __restrict__ Tp)
{
  int v = blockIdx.x & 255, j = blockIdx.x >> 8;
  int tid = threadIdx.x;
  __shared__ float e[128];
  if (tid < 128) e[tid] = emb_pcm[v*128+tid];
  __syncthreads();
  for (int g = tid; g < 1152; g += 256){
    const float* wrow = wih1 + g*512 + j*128;
    float acc = 0.f;
    for (int i=0;i<128;i+=4){
      float4 u = *(const float4*)(wrow + i);
      acc += u.x*e[i+0]+u.y*e[i+1]+u.z*e[i+2]+u.w*e[i+3];
    }
    int gate = g/384, jg = g - gate*384;
    Tp[(j*256+v)*1536 + jg*4 + gate] = acc;
  }
}

// ------- per-frame feature gate terms (incl. input bias) for GRU1 (packed) and GRU2
__global__ void __launch_bounds__(256) fg_kernel(
    const float* __restrict__ f,
    const float* __restrict__ wih1, const float* __restrict__ bih1,
    const float* __restrict__ wih2, const float* __restrict__ bih2,
    float* __restrict__ Fg1p, float* __restrict__ Fg2)
{
  int bf_ = blockIdx.x; // b*15 + frame
  int tid = threadIdx.x;
  __shared__ float fr[128];
  if (tid < 128) fr[tid] = f[bf_*128+tid];
  __syncthreads();
  for (int g = tid; g < 1152; g += 256){
    const float* wrow = wih1 + g*512 + 384;
    float acc = bih1[g];
    for (int i=0;i<128;i+=4){
      float4 u = *(const float4*)(wrow + i);
      acc += u.x*fr[i+0]+u.y*fr[i+1]+u.z*fr[i+2]+u.w*fr[i+3];
    }
    int gate = g/384, jg = g - gate*384;
    Fg1p[bf_*1536 + jg*4 + gate] = acc;
  }
  if (tid < 48){
    const float* wrow = wih2 + tid*512 + 384;
    float acc = bih2[tid];
    for (int i=0;i<128;i+=4){
      float4 u = *(const float4*)(wrow + i);
      acc += u.x*fr[i+0]+u.y*fr[i+1]+u.z*fr[i+2]+u.w*fr[i+3];
    }
    Fg2[bf_*48+tid] = acc;
  }
}

// ------- GRU1 scan: 24 persistent 1-wave blocks.
// h-exchange: self-tagged 8B words {2 x bf16, u32 step tag} moved with RELAXED
// agent-scope 64-bit atomics. No fences, no flags: validity travels with data.
// Parity double-buffer; tags make stale reads detectable ({t-2, t} only).
__global__ void __launch_bounds__(64,1) gru1_scan(
    const int* __restrict__ pcm, const float* __restrict__ whh,
    const float* __restrict__ bhh,
    const float* __restrict__ Tp, const float* __restrict__ Fg1p,
    unsigned long long* __restrict__ hbuf,
    unsigned short* __restrict__ out1)
{
  int blk = blockIdx.x;
  int l = threadIdx.x;
  int q = l >> 4, n = l & 15;
  int jg = blk*16 + n;
  int jg4 = jg*4;
  bool evenlane = ((n & 1) == 0);
  int wstore = blk*8 + (n >> 1);   // word index along dim axis for stores

  // b-fragments: W[gate][kk] : B[k][n'] = whh[gate*384 + jg][kk*32 + q*8 + i]  (fp32 -> bf16)
  bf16x8 W[3][12];
#pragma unroll
  for (int gate=0; gate<3; ++gate){
    const float* wr = whh + (gate*384 + jg)*384;
#pragma unroll
    for (int kk=0; kk<12; ++kk){
#pragma unroll
      for (int jj=0; jj<8; ++jj) W[gate][kk][jj] = (short)f2bf(wr[kk*32 + q*8 + jj]);
    }
  }
  float bhr = bhh[jg], bhz = bhh[384+jg], bhn = bhh[768+jg];
  float hown[4] = {0.f,0.f,0.f,0.f};
  const float* T1p = Tp + 256*1536;
  const float* T2p = Tp + 2*256*1536;
  int frame = 0, cnt = 0;

  // ---------- step t = 1 (h0 = 0: gh term is bias only) ----------
  {
    float xr[4], xz[4], xn[4];
#pragma unroll
    for (int r=0;r<4;++r){
      int b = (q<<2) + r;
      const int* pp = pcm + (b*2400 + 0)*3;
      int i0 = pp[0], i1 = pp[1], i2 = pp[2];
      float4 a0 = *(const float4*)(Tp  + i0*1536 + jg4);
      float4 a1 = *(const float4*)(T1p + i1*1536 + jg4);
      float4 a2 = *(const float4*)(T2p + i2*1536 + jg4);
      float4 af = *(const float4*)(Fg1p + (b*15+0)*1536 + jg4);
      xr[r] = a0.x+a1.x+a2.x+af.x;
      xz[r] = a0.y+a1.y+a2.y+af.y;
      xn[r] = a0.z+a1.z+a2.z+af.z;
    }
    float hnew[4];
    unsigned short hb16[4];
#pragma unroll
    for (int r=0;r<4;++r){
      float rg = sigm(xr[r]+bhr);
      float zg = sigm(xz[r]+bhz);
      float ng = tanh_(xn[r]+rg*bhn);
      float h = (1.f-zg)*ng;   // + zg*0
      hown[r] = h; hnew[r] = h; hb16[r] = f2bf(h);
    }
    unsigned long long* dst = hbuf + (1&1)*3072;
#pragma unroll
    for (int r=0;r<4;++r){
      float partner = __shfl_xor(hnew[r], 1);
      if (evenlane){
        unsigned int lo = (unsigned int)hb16[r] | ((unsigned int)f2bf(partner) << 16);
        unsigned long long wv = ((unsigned long long)1u << 32) | lo;
        __hip_atomic_store(dst + ((q<<2)+r)*192 + wstore, wv, __ATOMIC_RELAXED, __HIP_MEMORY_SCOPE_AGENT);
      }
    }
#pragma unroll
    for (int r=0;r<4;++r) out1[(((q<<2)+r)*2400 + 0)*384 + jg] = hb16[r];
    cnt = 1;
  }

  // ---------- steps t = 2..2400 ----------
  for (int t = 2; t <= 2400; ++t){
    int tt = t-1;
    unsigned int tag = (unsigned int)tt;
    int p = tt & 1;
    const unsigned long long* hb = hbuf + p*3072 + n*192;

    // 1) issue full h sweep (critical path) — 48 b64 atomic loads
    unsigned long long w[48];
#pragma unroll
    for (int kk=0;kk<12;++kk){
#pragma unroll
      for (int i=0;i<4;++i)
        w[kk*4+i] = __hip_atomic_load(hb + kk*16 + q*4 + i, __ATOMIC_RELAXED, __HIP_MEMORY_SCOPE_AGENT);
    }

    // 2) gx gather (independent of h; overlaps the poll)
    float xr[4], xz[4], xn[4];
#pragma unroll
    for (int r=0;r<4;++r){
      int b = (q<<2) + r;
      const int* pp = pcm + (b*2400 + tt)*3;
      int i0 = pp[0], i1 = pp[1], i2 = pp[2];
      float4 a0 = *(const float4*)(Tp  + i0*1536 + jg4);
      float4 a1 = *(const float4*)(T1p + i1*1536 + jg4);
      float4 a2 = *(const float4*)(T2p + i2*1536 + jg4);
      float4 af = *(const float4*)(Fg1p + (b*15+frame)*1536 + jg4);
      xr[r] = a0.x+a1.x+a2.x+af.x;
      xz[r] = a0.y+a1.y+a2.y+af.y;
      xn[r] = a0.z+a1.z+a2.z+af.z;
    }

    // 3) poll: re-load words whose tag hasn't reached tt yet
    for (;;){
      int bad = 0;
#pragma unroll
      for (int s=0;s<48;++s){
        if ((unsigned int)(w[s] >> 32) != tag){
          w[s] = __hip_atomic_load(hb + (s>>2)*16 + q*4 + (s&3), __ATOMIC_RELAXED, __HIP_MEMORY_SCOPE_AGENT);
          bad = 1;
        }
      }
      if (!__any(bad)) break;
    }

    // 4) repack low halves -> A-fragments, 36 MFMAs (3 independent chains)
    f32x4 accr = {0.f,0.f,0.f,0.f}, accz = {0.f,0.f,0.f,0.f}, accn = {0.f,0.f,0.f,0.f};
#pragma unroll
    for (int kk=0;kk<12;++kk){
      union { bf16x8 v; unsigned int u[4]; } a;
      a.u[0] = (unsigned int)w[kk*4+0];
      a.u[1] = (unsigned int)w[kk*4+1];
      a.u[2] = (unsigned int)w[kk*4+2];
      a.u[3] = (unsigned int)w[kk*4+3];
      accr = __builtin_amdgcn_mfma_f32_16x16x32_bf16(a.v, W[0][kk], accr, 0,0,0);
      accz = __builtin_amdgcn_mfma_f32_16x16x32_bf16(a.v, W[1][kk], accz, 0,0,0);
      accn = __builtin_amdgcn_mfma_f32_16x16x32_bf16(a.v, W[2][kk], accn, 0,0,0);
    }

    // 5) gates, publish h (tagged atomic words first), then out1
    float hnew[4];
    unsigned short hb16[4];
#pragma unroll
    for (int r=0;r<4;++r){
      float hr = accr[r]+bhr, hz = accz[r]+bhz, hn_ = accn[r]+bhn;
      float rg = sigm(xr[r]+hr);
      float zg = sigm(xz[r]+hz);
      float ng = tanh_(xn[r]+rg*hn_);
      float h = (1.f-zg)*ng + zg*hown[r];
      hown[r] = h; hnew[r] = h; hb16[r] = f2bf(h);
    }
    unsigned long long* dst = hbuf + (t&1)*3072;
#pragma unroll
    for (int r=0;r<4;++r){
      float partner = __shfl_xor(hnew[r], 1);
      if (evenlane){
        unsigned int lo = (unsigned int)hb16[r] | ((unsigned int)f2bf(partner) << 16);
        unsigned long long wv = ((unsigned long long)(unsigned int)t << 32) | lo;
        __hip_atomic_store(dst + ((q<<2)+r)*192 + wstore, wv, __ATOMIC_RELAXED, __HIP_MEMORY_SCOPE_AGENT);
      }
    }
#pragma unroll
    for (int r=0;r<4;++r) out1[(((q<<2)+r)*2400 + tt)*384 + jg] = hb16[r];

    if (++cnt == 160){ cnt = 0; ++frame; }
  }
}

// ------- gx2 = out1 @ g2_wih[:, :384].T + Fg2 (bias folded in Fg2)
__global__ void __launch_bounds__(256) gx2_kernel(
    const unsigned short* __restrict__ out1, const float* __restrict__ wih2,
    const float* __restrict__ Fg2, float* __restrict__ gx2)
{
  int tile = blockIdx.x, b = blockIdx.y;
  int tid = threadIdx.x;
  __shared__ float wl[48*388];
  __shared__ unsigned short xl[16*392];
  for (int v = tid; v < 48*96; v += 256){
    int row = v/96, c4 = (v - row*96)*4;
    *(float4*)(wl + row*388 + c4) = *(const float4*)(wih2 + row*512 + c4);
  }
  for (int v = tid; v < 16*48; v += 256){
    int row = v/48, c8 = (v - row*48)*8;
    *(uint4*)(xl + row*392 + c8) = *(const uint4*)(out1 + (b*2400 + tile*16 + row)*384 + c8);
  }
  __syncthreads();
  for (int o = tid; o < 768; o += 256){
    int g = o >> 4, tl = o & 15;            // consecutive threads share g -> broadcast reads
    int tg = tile*16 + tl, fr = tg/160;
    float acc = Fg2[(b*15+fr)*48 + g];
    const unsigned short* xp = xl + tl*392;
    const float* wp = wl + g*388;
    for (int i=0;i<384;++i){
      union { unsigned int u; float f; } cv; cv.u = ((unsigned int)xp[i]) << 16;
      acc += cv.f * wp[i];
    }
    gx2[(b*2400+tg)*48 + g] = acc;
  }
}

// ------- GRU2 scan: 16 blocks (1 batch each), zero-padded 16x16x32 MFMA
__global__ void __launch_bounds__(64) gru2_scan(
    const float* __restrict__ gx2, const float* __restrict__ whh2,
    const float* __restrict__ bhh2, float* __restrict__ out2)
{
  int b = blockIdx.x, l = threadIdx.x;
  int q = l >> 4, n = l & 15;
  __shared__ unsigned short hs[32];
  __shared__ float gxs[16*48];
  if (l < 32) hs[l] = 0;
  bf16x8 Wr = {0,0,0,0,0,0,0,0}, Wz = {0,0,0,0,0,0,0,0}, Wn = {0,0,0,0,0,0,0,0};
  if (q < 2){
#pragma unroll
    for (int jj=0; jj<8; ++jj){
      Wr[jj] = (short)f2bf(whh2[(n)*16 + q*8 + jj]);
      Wz[jj] = (short)f2bf(whh2[(16+n)*16 + q*8 + jj]);
      Wn[jj] = (short)f2bf(whh2[(32+n)*16 + q*8 + jj]);
    }
  }
  float bh_r=0.f, bh_z=0.f, bh_n=0.f, h=0.f;
  if (l < 16){ bh_r = bhh2[l]; bh_z = bhh2[16+l]; bh_n = bhh2[32+l]; }
  const float* src = gx2 + b*2400*48;
  float4 p0 = ((const float4*)src)[l];
  float4 p1 = ((const float4*)src)[l+64];
  float4 p2 = ((const float4*)src)[l+128];
  __syncthreads();
  for (int t=0; t<2400; ++t){
    int ph = t & 15;
    if (ph == 0){
      __syncthreads();
      ((float4*)gxs)[l] = p0; ((float4*)gxs)[l+64] = p1; ((float4*)gxs)[l+128] = p2;
      if (t+16 < 2400){
        const float4* s2 = (const float4*)(src + (t+16)*48);
        p0 = s2[l]; p1 = s2[l+64]; p2 = s2[l+128];
      }
      __syncthreads();
    }
    bf16x8 a = {0,0,0,0,0,0,0,0};
    if (n == 0) a = *(const bf16x8*)(hs + q*8);
    f32x4 z4 = {0.f,0.f,0.f,0.f};
    f32x4 dr = __builtin_amdgcn_mfma_f32_16x16x32_bf16(a, Wr, z4, 0,0,0);
    f32x4 dz = __builtin_amdgcn_mfma_f32_16x16x32_bf16(a, Wz, z4, 0,0,0);
    f32x4 dn = __builtin_amdgcn_mfma_f32_16x16x32_bf16(a, Wn, z4, 0,0,0);
    if (l < 16){
      const float* g = gxs + ph*48;
      float rg = sigm(g[l] + dr[0] + bh_r);
      float zg = sigm(g[16+l] + dz[0] + bh_z);
      float ng = tanh_(g[32+l] + rg*(dn[0] + bh_n));
      h = (1.f - zg)*ng + zg*h;
      hs[l] = f2bf(h);
      out2[(b*2400+t)*16 + l] = h;
    }
    __syncthreads();
  }
}

// ------- MDense head
__global__ void __launch_bounds__(256) head_kernel(
    const float* __restrict__ out2,
    const float* __restrict__ fc1w, const float* __restrict__ fc1b,
    const float* __restrict__ fc2w, const float* __restrict__ fc2b,
    const float* __restrict__ g1, const float* __restrict__ g2,
    float* __restrict__ out)
{
  int blk = blockIdx.x;
  int b = blk/150, tile = blk - b*150;
  int c = threadIdx.x;
  __shared__ float s[256];
  float w1[16], w2[16];
#pragma unroll
  for (int k=0;k<16;k+=4){
    float4 u = *(const float4*)(fc1w + c*16 + k);
    w1[k]=u.x; w1[k+1]=u.y; w1[k+2]=u.z; w1[k+3]=u.w;
    float4 v = *(const float4*)(fc2w + c*16 + k);
    w2[k]=v.x; w2[k+1]=v.y; w2[k+2]=v.z; w2[k+3]=v.w;
  }
  float b1 = fc1b[c], b2 = fc2b[c];
  float ga = g1[c], gb = g2[c];
  int base = b*2400 + tile*16;
  s[c] = out2[base*16 + c];
  __syncthreads();
  for (int tl=0; tl<16; ++tl){
    float a1=b1, a2=b2;
#pragma unroll
    for (int k=0;k<16;++k){ float x = s[tl*16+k]; a1 += x*w1[k]; a2 += x*w2[k]; }
    float y = ga*tanh_(a1) + gb*tanh_(a2);
    out[(base+tl)*256 + c] = y;
  }
}

extern "C" void kernel_launch(void* const* d_in, const int* in_sizes, int n_in,
                              void* d_out, int out_size, void* d_ws, size_t ws_size,
                              hipStream_t stream)
{
  const int*   pcm      = (const int*)d_in[0];
  const float* feat     = (const float*)d_in[1];
  const int*   pitch    = (const int*)d_in[2];
  const float* emb_pcm  = (const float*)d_in[3];
  const float* emb_pit  = (const float*)d_in[4];
  const float* conv1_w  = (const float*)d_in[5];
  const float* conv1_b  = (const float*)d_in[6];
  const float* conv2_w  = (const float*)d_in[7];
  const float* conv2_b  = (const float*)d_in[8];
  const float* d1_w     = (const float*)d_in[9];
  const float* d1_b     = (const float*)d_in[10];
  const float* d2_w     = (const float*)d_in[11];
  const float* d2_b     = (const float*)d_in[12];
  const float* g1_wih   = (const float*)d_in[13];
  const float* g1_whh   = (const float*)d_in[14];
  const float* g1_bih   = (const float*)d_in[15];
  const float* g1_bhh   = (const float*)d_in[16];
  const float* g2_wih   = (const float*)d_in[17];
  const float* g2_whh   = (const float*)d_in[18];
  const float* g2_bih   = (const float*)d_in[19];
  const float* g2_bhh   = (const float*)d_in[20];
  const float* fc1_w    = (const float*)d_in[21];
  const float* fc1_b    = (const float*)d_in[22];
  const float* fc2_w    = (const float*)d_in[23];
  const float* fc2_b    = (const float*)d_in[24];
  const float* gamma1   = (const float*)d_in[25];
  const float* gamma2   = (const float*)d_in[26];

  char* ws = (char*)d_ws;
  float*              f_ws  = (float*)(ws + 0);                 //  122880 B
  float*              Tp    = (float*)(ws + 131072);            //  4718592 B
  float*              Fg1p  = (float*)(ws + 4849664);           //  1474560 B
  float*              Fg2   = (float*)(ws + 6324224);           //  46080 B
  unsigned long long* hbuf  = (unsigned long long*)(ws + 6370304); // 49152 B (tags self-init vs 0xAA poison)
  unsigned short*     out1  = (unsigned short*)(ws + 6419456);  //  29491200 B
  float*              gx2   = (float*)(ws + 35910656);          //  7372800 B
  float*              out2  = (float*)(ws + 43283456);          //  2457600 B (end ~45.7 MB)

  encoder_kernel<<<16, 128, 0, stream>>>(feat, pitch, emb_pit, conv1_w, conv1_b,
                                         conv2_w, conv2_b, d1_w, d1_b, d2_w, d2_b, f_ws);
  tables_kernel<<<768, 256, 0, stream>>>(emb_pcm, g1_wih, Tp);
  fg_kernel<<<240, 256, 0, stream>>>(f_ws, g1_wih, g1_bih, g2_wih, g2_bih, Fg1p, Fg2);
  gru1_scan<<<NB1, 64, 0, stream>>>(pcm, g1_whh, g1_bhh, Tp, Fg1p, hbuf, out1);
  gx2_kernel<<<dim3(150,16), 256, 0, stream>>>(out1, g2_wih, Fg2, gx2);
  gru2_scan<<<16, 64, 0, stream>>>(gx2, g2_whh, g2_bhh, out2);
  head_kernel<<<2400, 256, 0, stream>>>(out2, fc1_w, fc1_b, fc2_w, fc2_b, gamma1, gamma2,
                                        (float*)d_out);
}

// Round 6
// 11598.766 us; speedup vs baseline: 1.1609x; 1.1060x over previous
//
#include <hip/hip_runtime.h>
#include <hip/hip_bf16.h>
#include <math.h>

typedef __attribute__((ext_vector_type(4))) float f32x4;
typedef __attribute__((ext_vector_type(8))) short bf16x8;
typedef __attribute__((ext_vector_type(4))) unsigned int u32x4;

#define NB1 24   // blocks in GRU1 scan: 24 x 16 h-indices = 384

__device__ __forceinline__ unsigned short f2bf(float f){
  union { float f; unsigned int i; } c; c.f = f;
  return (unsigned short)((c.i + 0x7fffu + ((c.i >> 16) & 1u)) >> 16);
}
__device__ __forceinline__ float sigm(float x){
  return 1.0f / (1.0f + exp2f(-1.4426950408889634f * x));
}
__device__ __forceinline__ float tanh_(float x){
  float e = exp2f(2.8853900817779268f * x);
  return 1.0f - 2.0f / (e + 1.0f);
}

// ---------------- encoder: pitch-emb concat -> conv1 -> conv2 -> d1 -> d2 ----
__global__ void __launch_bounds__(128) encoder_kernel(
    const float* __restrict__ feat, const int* __restrict__ pitch,
    const float* __restrict__ emb_pitch,
    const float* __restrict__ w1, const float* __restrict__ b1,
    const float* __restrict__ w2, const float* __restrict__ b2,
    const float* __restrict__ d1w, const float* __restrict__ d1b,
    const float* __restrict__ d2w, const float* __restrict__ d2b,
    float* __restrict__ fout)
{
  int b = blockIdx.x, tid = threadIdx.x;
  __shared__ float xin[19][104];
  __shared__ float t1[17][128];
  __shared__ float t2[15][128];
  __shared__ float t3[15][128];
  for (int idx = tid; idx < 19*38; idx += 128){ int l = idx/38, c = idx-l*38; xin[l][c] = feat[(b*19+l)*38+c]; }
  for (int idx = tid; idx < 19*64; idx += 128){ int l = idx/64, c = idx-l*64; xin[l][38+c] = emb_pitch[pitch[b*19+l]*64+c]; }
  __syncthreads();
  { // conv1: 102ch, k=3, VALID -> 17 x 128
    int c = tid;
    float acc[17];
    float bias = b1[c];
#pragma unroll
    for (int l=0;l<17;++l) acc[l]=bias;
    for (int i=0;i<102;++i){
      const float* wp = w1 + (c*102+i)*3;
      float w0 = wp[0], wk1 = wp[1], wk2 = wp[2];
      float x[19];
#pragma unroll
      for (int l=0;l<19;++l) x[l]=xin[l][i];
#pragma unroll
      for (int l=0;l<17;++l) acc[l] += w0*x[l] + wk1*x[l+1] + wk2*x[l+2];
    }
#pragma unroll
    for (int l=0;l<17;++l) t1[l][c] = tanh_(acc[l]);
  }
  __syncthreads();
  { // conv2
    int c = tid;
    float acc[15];
    float bias = b2[c];
#pragma unroll
    for (int l=0;l<15;++l) acc[l]=bias;
    for (int i=0;i<128;++i){
      const float* wp = w2 + (c*128+i)*3;
      float w0 = wp[0], wk1 = wp[1], wk2 = wp[2];
      float x[17];
#pragma unroll
      for (int l=0;l<17;++l) x[l]=t1[l][i];
#pragma unroll
      for (int l=0;l<15;++l) acc[l] += w0*x[l] + wk1*x[l+1] + wk2*x[l+2];
    }
#pragma unroll
    for (int l=0;l<15;++l) t2[l][c] = tanh_(acc[l]);
  }
  __syncthreads();
  { // dense1
    int c = tid;
    float acc[15];
    float bias = d1b[c];
#pragma unroll
    for (int l=0;l<15;++l) acc[l]=bias;
    for (int i=0;i<128;++i){
      float w = d1w[c*128+i];
#pragma unroll
      for (int l=0;l<15;++l) acc[l] += w*t2[l][i];
    }
#pragma unroll
    for (int l=0;l<15;++l) t3[l][c] = tanh_(acc[l]);
  }
  __syncthreads();
  { // dense2 -> fout [b][15][128] fp32
    int c = tid;
    float acc[15];
    float bias = d2b[c];
#pragma unroll
    for (int l=0;l<15;++l) acc[l]=bias;
    for (int i=0;i<128;++i){
      float w = d2w[c*128+i];
#pragma unroll
      for (int l=0;l<15;++l) acc[l] += w*t3[l][i];
    }
#pragma unroll
    for (int l=0;l<15;++l) fout[(b*15+l)*128+c] = tanh_(acc[l]);
  }
}

// ------- tables: Tp[j][v][jg][gate] = sum_i emb_pcm[v][i]*g1_wih[gate*384+jg][128j+i]
__global__ void __launch_bounds__(256) tables_kernel(
    const float* __restrict__ emb_pcm, const float* __restrict__ wih1,
    float* __restrict__ Tp)
{
  int v = blockIdx.x & 255, j = blockIdx.x >> 8;
  int tid = threadIdx.x;
  __shared__ float e[128];
  if (tid < 128) e[tid] = emb_pcm[v*128+tid];
  __syncthreads();
  for (int g = tid; g < 1152; g += 256){
    const float* wrow = wih1 + g*512 + j*128;
    float acc = 0.f;
    for (int i=0;i<128;i+=4){
      float4 u = *(const float4*)(wrow + i);
      acc += u.x*e[i+0]+u.y*e[i+1]+u.z*e[i+2]+u.w*e[i+3];
    }
    int gate = g/384, jg = g - gate*384;
    Tp[(j*256+v)*1536 + jg*4 + gate] = acc;
  }
}

// ------- per-frame feature gate terms (incl. input bias) for GRU1 (packed) and GRU2
__global__ void __launch_bounds__(256) fg_kernel(
    const float* __restrict__ f,
    const float* __restrict__ wih1, const float* __restrict__ bih1,
    const float* __restrict__ wih2, const float* __restrict__ bih2,
    float* __restrict__ Fg1p, float* __restrict__ Fg2)
{
  int bf_ = blockIdx.x; // b*15 + frame
  int tid = threadIdx.x;
  __shared__ float fr[128];
  if (tid < 128) fr[tid] = f[bf_*128+tid];
  __syncthreads();
  for (int g = tid; g < 1152; g += 256){
    const float* wrow = wih1 + g*512 + 384;
    float acc = bih1[g];
    for (int i=0;i<128;i+=4){
      float4 u = *(const float4*)(wrow + i);
      acc += u.x*fr[i+0]+u.y*fr[i+1]+u.z*fr[i+2]+u.w*fr[i+3];
    }
    int gate = g/384, jg = g - gate*384;
    Fg1p[bf_*1536 + jg*4 + gate] = acc;
  }
  if (tid < 48){
    const float* wrow = wih2 + tid*512 + 384;
    float acc = bih2[tid];
    for (int i=0;i<128;i+=4){
      float4 u = *(const float4*)(wrow + i);
      acc += u.x*fr[i+0]+u.y*fr[i+1]+u.z*fr[i+2]+u.w*fr[i+3];
    }
    Fg2[bf_*48+tid] = acc;
  }
}

// ------- GRU1 scan: 24 persistent 1-wave blocks (any placement).
// h-exchange: {2 x bf16, u32 step-tag} 8B words; writers use RELAXED AGENT-scope
// atomic stores (proven visible in R3), readers sweep all 48 words with ONE
// batched asm block (24 x dwordx4, agent-scope sc1, single vmcnt) per pass.
__global__ void __launch_bounds__(64,1) gru1_scan(
    const int* __restrict__ pcm, const float* __restrict__ whh,
    const float* __restrict__ bhh,
    const float* __restrict__ Tp, const float* __restrict__ Fg1p,
    unsigned long long* __restrict__ hbuf,
    unsigned short* __restrict__ out1)
{
  int blk = blockIdx.x;
  int l = threadIdx.x;
  int q = l >> 4, n = l & 15;
  int jg = blk*16 + n;
  int jg4 = jg*4;
  bool evenlane = ((n & 1) == 0);
  int wstore = blk*8 + (n >> 1);   // word index along dim axis for stores

  // b-fragments: W[gate][kk] : B[k][n'] = whh[gate*384 + jg][kk*32 + q*8 + i]  (fp32 -> bf16)
  bf16x8 W[3][12];
#pragma unroll
  for (int gate=0; gate<3; ++gate){
    const float* wr = whh + (gate*384 + jg)*384;
#pragma unroll
    for (int kk=0; kk<12; ++kk){
#pragma unroll
      for (int jj=0; jj<8; ++jj) W[gate][kk][jj] = (short)f2bf(wr[kk*32 + q*8 + jj]);
    }
  }
  float bhr = bhh[jg], bhz = bhh[384+jg], bhn = bhh[768+jg];
  float hown[4] = {0.f,0.f,0.f,0.f};
  const float* T1p = Tp + 256*1536;
  const float* T2p = Tp + 2*256*1536;
  int frame = 0, cnt = 0;

  // ---------- step t = 1 (h0 = 0: gh term is bias only) ----------
  {
    float xr[4], xz[4], xn[4];
#pragma unroll
    for (int r=0;r<4;++r){
      int b = (q<<2) + r;
      const int* pp = pcm + (b*2400 + 0)*3;
      int i0 = pp[0], i1 = pp[1], i2 = pp[2];
      float4 a0 = *(const float4*)(Tp  + i0*1536 + jg4);
      float4 a1 = *(const float4*)(T1p + i1*1536 + jg4);
      float4 a2 = *(const float4*)(T2p + i2*1536 + jg4);
      float4 af = *(const float4*)(Fg1p + (b*15+0)*1536 + jg4);
      xr[r] = a0.x+a1.x+a2.x+af.x;
      xz[r] = a0.y+a1.y+a2.y+af.y;
      xn[r] = a0.z+a1.z+a2.z+af.z;
    }
    float hnew[4];
    unsigned short hb16[4];
#pragma unroll
    for (int r=0;r<4;++r){
      float rg = sigm(xr[r]+bhr);
      float zg = sigm(xz[r]+bhz);
      float ng = tanh_(xn[r]+rg*bhn);
      float h = (1.f-zg)*ng;   // + zg*0
      hown[r] = h; hnew[r] = h; hb16[r] = f2bf(h);
    }
    unsigned long long* dst = hbuf + (1&1)*3072;
#pragma unroll
    for (int r=0;r<4;++r){
      float partner = __shfl_xor(hnew[r], 1);
      if (evenlane){
        unsigned int lo = (unsigned int)hb16[r] | ((unsigned int)f2bf(partner) << 16);
        unsigned long long wv = ((unsigned long long)1u << 32) | lo;
        __hip_atomic_store(dst + ((q<<2)+r)*192 + wstore, wv, __ATOMIC_RELAXED, __HIP_MEMORY_SCOPE_AGENT);
      }
    }
#pragma unroll
    for (int r=0;r<4;++r) out1[(((q<<2)+r)*2400 + 0)*384 + jg] = hb16[r];
    cnt = 1;
  }

  // ---------- steps t = 2..2400 ----------
  for (int t = 2; t <= 2400; ++t){
    int tt = t-1;
    unsigned int tag = (unsigned int)tt;
    int p = tt & 1;
    // per-lane base: batch row n, word q*4  (16 u64 per kk-block of 32 dims)
    const unsigned long long* hb = hbuf + p*3072 + n*192 + q*4;

    // gx gather (independent of h; overlaps the first poll sweep)
    float xr[4], xz[4], xn[4];
#pragma unroll
    for (int r=0;r<4;++r){
      int b = (q<<2) + r;
      const int* pp = pcm + (b*2400 + tt)*3;
      int i0 = pp[0], i1 = pp[1], i2 = pp[2];
      float4 a0 = *(const float4*)(Tp  + i0*1536 + jg4);
      float4 a1 = *(const float4*)(T1p + i1*1536 + jg4);
      float4 a2 = *(const float4*)(T2p + i2*1536 + jg4);
      float4 af = *(const float4*)(Fg1p + (b*15+frame)*1536 + jg4);
      xr[r] = a0.x+a1.x+a2.x+af.x;
      xz[r] = a0.y+a1.y+a2.y+af.y;
      xn[r] = a0.z+a1.z+a2.z+af.z;
    }

    // poll: one batched agent-scope (sc1) sweep of 48 tagged words per pass,
    // single vmcnt. Earlyclobber outputs (must not alias the address input).
    u32x4 o[24];
    for (int spin = 0; spin < (1<<12); ++spin){
      asm volatile(
        "global_load_dwordx4 %0, %24, off sc1\n\t"
        "global_load_dwordx4 %1, %24, off offset:16 sc1\n\t"
        "global_load_dwordx4 %2, %24, off offset:128 sc1\n\t"
        "global_load_dwordx4 %3, %24, off offset:144 sc1\n\t"
        "global_load_dwordx4 %4, %24, off offset:256 sc1\n\t"
        "global_load_dwordx4 %5, %24, off offset:272 sc1\n\t"
        "global_load_dwordx4 %6, %24, off offset:384 sc1\n\t"
        "global_load_dwordx4 %7, %24, off offset:400 sc1\n\t"
        "global_load_dwordx4 %8, %24, off offset:512 sc1\n\t"
        "global_load_dwordx4 %9, %24, off offset:528 sc1\n\t"
        "global_load_dwordx4 %10, %24, off offset:640 sc1\n\t"
        "global_load_dwordx4 %11, %24, off offset:656 sc1\n\t"
        "global_load_dwordx4 %12, %24, off offset:768 sc1\n\t"
        "global_load_dwordx4 %13, %24, off offset:784 sc1\n\t"
        "global_load_dwordx4 %14, %24, off offset:896 sc1\n\t"
        "global_load_dwordx4 %15, %24, off offset:912 sc1\n\t"
        "global_load_dwordx4 %16, %24, off offset:1024 sc1\n\t"
        "global_load_dwordx4 %17, %24, off offset:1040 sc1\n\t"
        "global_load_dwordx4 %18, %24, off offset:1152 sc1\n\t"
        "global_load_dwordx4 %19, %24, off offset:1168 sc1\n\t"
        "global_load_dwordx4 %20, %24, off offset:1280 sc1\n\t"
        "global_load_dwordx4 %21, %24, off offset:1296 sc1\n\t"
        "global_load_dwordx4 %22, %24, off offset:1408 sc1\n\t"
        "global_load_dwordx4 %23, %24, off offset:1424 sc1\n\t"
        "s_waitcnt vmcnt(0)"
        : "=&v"(o[0]),"=&v"(o[1]),"=&v"(o[2]),"=&v"(o[3]),"=&v"(o[4]),"=&v"(o[5]),
          "=&v"(o[6]),"=&v"(o[7]),"=&v"(o[8]),"=&v"(o[9]),"=&v"(o[10]),"=&v"(o[11]),
          "=&v"(o[12]),"=&v"(o[13]),"=&v"(o[14]),"=&v"(o[15]),"=&v"(o[16]),"=&v"(o[17]),
          "=&v"(o[18]),"=&v"(o[19]),"=&v"(o[20]),"=&v"(o[21]),"=&v"(o[22]),"=&v"(o[23])
        : "v"(hb) : "memory");
      unsigned int bad = 0;
#pragma unroll
      for (int s=0;s<24;++s) bad |= (o[s].y ^ tag) | (o[s].w ^ tag);
      if (!__any(bad != 0)) break;
    }

    // repack value halves -> A-fragments, 36 MFMAs (3 independent chains)
    f32x4 accr = {0.f,0.f,0.f,0.f}, accz = {0.f,0.f,0.f,0.f}, accn = {0.f,0.f,0.f,0.f};
#pragma unroll
    for (int kk=0;kk<12;++kk){
      union { bf16x8 v; unsigned int u[4]; } a;
      a.u[0] = o[2*kk].x;
      a.u[1] = o[2*kk].z;
      a.u[2] = o[2*kk+1].x;
      a.u[3] = o[2*kk+1].z;
      accr = __builtin_amdgcn_mfma_f32_16x16x32_bf16(a.v, W[0][kk], accr, 0,0,0);
      accz = __builtin_amdgcn_mfma_f32_16x16x32_bf16(a.v, W[1][kk], accz, 0,0,0);
      accn = __builtin_amdgcn_mfma_f32_16x16x32_bf16(a.v, W[2][kk], accn, 0,0,0);
    }

    // gates, publish h (tagged agent-scope atomic stores), then out1
    float hnew[4];
    unsigned short hb16[4];
#pragma unroll
    for (int r=0;r<4;++r){
      float hr = accr[r]+bhr, hz = accz[r]+bhz, hn_ = accn[r]+bhn;
      float rg = sigm(xr[r]+hr);
      float zg = sigm(xz[r]+hz);
      float ng = tanh_(xn[r]+rg*hn_);
      float h = (1.f-zg)*ng + zg*hown[r];
      hown[r] = h; hnew[r] = h; hb16[r] = f2bf(h);
    }
    unsigned long long* dst = hbuf + (t&1)*3072;
#pragma unroll
    for (int r=0;r<4;++r){
      float partner = __shfl_xor(hnew[r], 1);
      if (evenlane){
        unsigned int lo = (unsigned int)hb16[r] | ((unsigned int)f2bf(partner) << 16);
        unsigned long long wv = ((unsigned long long)(unsigned int)t << 32) | lo;
        __hip_atomic_store(dst + ((q<<2)+r)*192 + wstore, wv, __ATOMIC_RELAXED, __HIP_MEMORY_SCOPE_AGENT);
      }
    }
#pragma unroll
    for (int r=0;r<4;++r) out1[(((q<<2)+r)*2400 + tt)*384 + jg] = hb16[r];

    if (++cnt == 160){ cnt = 0; ++frame; }
  }
}

// ------- gx2 = out1 @ g2_wih[:, :384].T + Fg2 (bias folded in Fg2)
__global__ void __launch_bounds__(256) gx2_kernel(
    const unsigned short* __restrict__ out1, const float* __restrict__ wih2,
    const float* __restrict__ Fg2, float* __restrict__ gx2)
{
  int tile = blockIdx.x, b = blockIdx.y;
  int tid = threadIdx.x;
  __shared__ float wl[48*388];
  __shared__ unsigned short xl[16*392];
  for (int v = tid; v < 48*96; v += 256){
    int row = v/96, c4 = (v - row*96)*4;
    *(float4*)(wl + row*388 + c4) = *(const float4*)(wih2 + row*512 + c4);
  }
  for (int v = tid; v < 16*48; v += 256){
    int row = v/48, c8 = (v - row*48)*8;
    *(uint4*)(xl + row*392 + c8) = *(const uint4*)(out1 + (b*2400 + tile*16 + row)*384 + c8);
  }
  __syncthreads();
  for (int o = tid; o < 768; o += 256){
    int g = o >> 4, tl = o & 15;            // consecutive threads share g -> broadcast reads
    int tg = tile*16 + tl, fr = tg/160;
    float acc = Fg2[(b*15+fr)*48 + g];
    const unsigned short* xp = xl + tl*392;
    const float* wp = wl + g*388;
    for (int i=0;i<384;++i){
      union { unsigned int u; float f; } cv; cv.u = ((unsigned int)xp[i]) << 16;
      acc += cv.f * wp[i];
    }
    gx2[(b*2400+tg)*48 + g] = acc;
  }
}

// ------- GRU2 scan: 16 blocks (1 batch each), zero-padded 16x16x32 MFMA
__global__ void __launch_bounds__(64) gru2_scan(
    const float* __restrict__ gx2, const float* __restrict__ whh2,
    const float* __restrict__ bhh2, float* __restrict__ out2)
{
  int b = blockIdx.x, l = threadIdx.x;
  int q = l >> 4, n = l & 15;
  __shared__ unsigned short hs[32];
  __shared__ float gxs[16*48];
  if (l < 32) hs[l] = 0;
  bf16x8 Wr = {0,0,0,0,0,0,0,0}, Wz = {0,0,0,0,0,0,0,0}, Wn = {0,0,0,0,0,0,0,0};
  if (q < 2){
#pragma unroll
    for (int jj=0; jj<8; ++jj){
      Wr[jj] = (short)f2bf(whh2[(n)*16 + q*8 + jj]);
      Wz[jj] = (short)f2bf(whh2[(16+n)*16 + q*8 + jj]);
      Wn[jj] = (short)f2bf(whh2[(32+n)*16 + q*8 + jj]);
    }
  }
  float bh_r=0.f, bh_z=0.f, bh_n=0.f, h=0.f;
  if (l < 16){ bh_r = bhh2[l]; bh_z = bhh2[16+l]; bh_n = bhh2[32+l]; }
  const float* src = gx2 + b*2400*48;
  float4 p0 = ((const float4*)src)[l];
  float4 p1 = ((const float4*)src)[l+64];
  float4 p2 = ((const float4*)src)[l+128];
  __syncthreads();
  for (int t=0; t<2400; ++t){
    int ph = t & 15;
    if (ph == 0){
      __syncthreads();
      ((float4*)gxs)[l] = p0; ((float4*)gxs)[l+64] = p1; ((float4*)gxs)[l+128] = p2;
      if (t+16 < 2400){
        const float4* s2 = (const float4*)(src + (t+16)*48);
        p0 = s2[l]; p1 = s2[l+64]; p2 = s2[l+128];
      }
      __syncthreads();
    }
    bf16x8 a = {0,0,0,0,0,0,0,0};
    if (n == 0) a = *(const bf16x8*)(hs + q*8);
    f32x4 z4 = {0.f,0.f,0.f,0.f};
    f32x4 dr = __builtin_amdgcn_mfma_f32_16x16x32_bf16(a, Wr, z4, 0,0,0);
    f32x4 dz = __builtin_amdgcn_mfma_f32_16x16x32_bf16(a, Wz, z4, 0,0,0);
    f32x4 dn = __builtin_amdgcn_mfma_f32_16x16x32_bf16(a, Wn, z4, 0,0,0);
    if (l < 16){
      const float* g = gxs + ph*48;
      float rg = sigm(g[l] + dr[0] + bh_r);
      float zg = sigm(g[16+l] + dz[0] + bh_z);
      float ng = tanh_(g[32+l] + rg*(dn[0] + bh_n));
      h = (1.f - zg)*ng + zg*h;
      hs[l] = f2bf(h);
      out2[(b*2400+t)*16 + l] = h;
    }
    __syncthreads();
  }
}

// ------- MDense head
__global__ void __launch_bounds__(256) head_kernel(
    const float* __restrict__ out2,
    const float* __restrict__ fc1w, const float* __restrict__ fc1b,
    const float* __restrict__ fc2w, const float* __restrict__ fc2b,
    const float* __restrict__ g1, const float* __restrict__ g2,
    float* __restrict__ out)
{
  int blk = blockIdx.x;
  int b = blk/150, tile = blk - b*150;
  int c = threadIdx.x;
  __shared__ float s[256];
  float w1[16], w2[16];
#pragma unroll
  for (int k=0;k<16;k+=4){
    float4 u = *(const float4*)(fc1w + c*16 + k);
    w1[k]=u.x; w1[k+1]=u.y; w1[k+2]=u.z; w1[k+3]=u.w;
    float4 v = *(const float4*)(fc2w + c*16 + k);
    w2[k]=v.x; w2[k+1]=v.y; w2[k+2]=v.z; w2[k+3]=v.w;
  }
  float b1 = fc1b[c], b2 = fc2b[c];
  float ga = g1[c], gb = g2[c];
  int base = b*2400 + tile*16;
  s[c] = out2[base*16 + c];
  __syncthreads();
  for (int tl=0; tl<16; ++tl){
    float a1=b1, a2=b2;
#pragma unroll
    for (int k=0;k<16;++k){ float x = s[tl*16+k]; a1 += x*w1[k]; a2 += x*w2[k]; }
    float y = ga*tanh_(a1) + gb*tanh_(a2);
    out[(base+tl)*256 + c] = y;
  }
}

extern "C" void kernel_launch(void* const* d_in, const int* in_sizes, int n_in,
                              void* d_out, int out_size, void* d_ws, size_t ws_size,
                              hipStream_t stream)
{
  const int*   pcm      = (const int*)d_in[0];
  const float* feat     = (const float*)d_in[1];
  const int*   pitch    = (const int*)d_in[2];
  const float* emb_pcm  = (const float*)d_in[3];
  const float* emb_pit  = (const float*)d_in[4];
  const float* conv1_w  = (const float*)d_in[5];
  const float* conv1_b  = (const float*)d_in[6];
  const float* conv2_w  = (const float*)d_in[7];
  const float* conv2_b  = (const float*)d_in[8];
  const float* d1_w     = (const float*)d_in[9];
  const float* d1_b     = (const float*)d_in[10];
  const float* d2_w     = (const float*)d_in[11];
  const float* d2_b     = (const float*)d_in[12];
  const float* g1_wih   = (const float*)d_in[13];
  const float* g1_whh   = (const float*)d_in[14];
  const float* g1_bih   = (const float*)d_in[15];
  const float* g1_bhh   = (const float*)d_in[16];
  const float* g2_wih   = (const float*)d_in[17];
  const float* g2_whh   = (const float*)d_in[18];
  const float* g2_bih   = (const float*)d_in[19];
  const float* g2_bhh   = (const float*)d_in[20];
  const float* fc1_w    = (const float*)d_in[21];
  const float* fc1_b    = (const float*)d_in[22];
  const float* fc2_w    = (const float*)d_in[23];
  const float* fc2_b    = (const float*)d_in[24];
  const float* gamma1   = (const float*)d_in[25];
  const float* gamma2   = (const float*)d_in[26];

  char* ws = (char*)d_ws;
  float*              f_ws  = (float*)(ws + 1024);              //  122880 B
  float*              Tp    = (float*)(ws + 131072);            //  4718592 B
  float*              Fg1p  = (float*)(ws + 4849664);           //  1474560 B
  float*              Fg2   = (float*)(ws + 6324224);           //  46080 B
  unsigned long long* hbuf  = (unsigned long long*)(ws + 6370304); // 49152 B (tags self-validate vs 0xAA poison)
  unsigned short*     out1  = (unsigned short*)(ws + 6419456);  //  29491200 B
  float*              gx2   = (float*)(ws + 35910656);          //  7372800 B
  float*              out2  = (float*)(ws + 43283456);          //  2457600 B (end ~45.7 MB)

  encoder_kernel<<<16, 128, 0, stream>>>(feat, pitch, emb_pit, conv1_w, conv1_b,
                                         conv2_w, conv2_b, d1_w, d1_b, d2_w, d2_b, f_ws);
  tables_kernel<<<768, 256, 0, stream>>>(emb_pcm, g1_wih, Tp);
  fg_kernel<<<240, 256, 0, stream>>>(f_ws, g1_wih, g1_bih, g2_wih, g2_bih, Fg1p, Fg2);
  gru1_scan<<<NB1, 64, 0, stream>>>(pcm, g1_whh, g1_bhh, Tp, Fg1p, hbuf, out1);
  gx2_kernel<<<dim3(150,16), 256, 0, stream>>>(out1, g2_wih, Fg2, gx2);
  gru2_scan<<<16, 64, 0, stream>>>(gx2, g2_whh, g2_bhh, out2);
  head_kernel<<<2400, 256, 0, stream>>>(out2, fc1_w, fc1_b, fc2_w, fc2_b, gamma1, gamma2,
                                        (float*)d_out);
}